// Round 8
// baseline (126.895 us; speedup 1.0000x reference)
//
#include <hip/hip_runtime.h>
#include <math.h>

#define U 8192
#define NITEMS 100000
#define H 50
#define QD 128
#define D 256
#define BMG 8      // rows per block in the thin GEMMs (grid = U/BMG = 1024)
#define NRMAX 13   // max rows per wave in attn: ceil(50/4)

// Full-wave (64-lane) sum via DPP, result broadcast through readlane(63).
__device__ __forceinline__ float wave_bcast_sum64(float x) {
    float t = x;
    int y;
    y = __builtin_amdgcn_update_dpp(0, __float_as_int(t), 0xB1, 0xF, 0xF, true); // quad_perm(1,0,3,2)
    t += __int_as_float(y);
    y = __builtin_amdgcn_update_dpp(0, __float_as_int(t), 0x4E, 0xF, 0xF, true); // quad_perm(2,3,0,1)
    t += __int_as_float(y);
    y = __builtin_amdgcn_update_dpp(0, __float_as_int(t), 0x124, 0xF, 0xF, true); // row_ror:4
    t += __int_as_float(y);
    y = __builtin_amdgcn_update_dpp(0, __float_as_int(t), 0x128, 0xF, 0xF, true); // row_ror:8
    t += __int_as_float(y);
    y = __builtin_amdgcn_update_dpp(0, __float_as_int(t), 0x142, 0xA, 0xF, true); // row_bcast:15
    t += __int_as_float(y);
    y = __builtin_amdgcn_update_dpp(0, __float_as_int(t), 0x143, 0xC, 0xF, true); // row_bcast:31
    t += __int_as_float(y);
    return __int_as_float(__builtin_amdgcn_readlane(__float_as_int(t), 63));
}

// broadcast block-reduce (256 threads = 4 waves) — kernel A only
__device__ __forceinline__ float block_reduce_256(float v, float* sred) {
    #pragma unroll
    for (int off = 32; off >= 1; off >>= 1)
        v += __shfl_xor(v, off, 64);
    int wave = threadIdx.x >> 6;
    int lane = threadIdx.x & 63;
    if (lane == 0) sred[wave] = v;
    __syncthreads();
    float s;
    if (threadIdx.x == 0) {
        s = sred[0] + sred[1] + sred[2] + sred[3];
        sred[0] = s;
    }
    __syncthreads();
    s = sred[0];
    __syncthreads();
    return s;
}

// Kernel A: M = Wq @ Wk^T [QD,D]; bqt = bq @ Wk^T [D]; wb = Wq @ bk [QD]; c0 = bq.bk
__global__ void __launch_bounds__(256) upa_precompute(
    const float* __restrict__ Wq, const float* __restrict__ bq,
    const float* __restrict__ Wk, const float* __restrict__ bk,
    float* __restrict__ M, float* __restrict__ bqt,
    float* __restrict__ wb, float* __restrict__ c0) {
    __shared__ float row[D];
    __shared__ float sred[4];
    int k = blockIdx.x;
    int t = threadIdx.x;
    if (k < QD) {
        row[t] = (t < D) ? Wq[k * D + t] : 0.f;
        __syncthreads();
        const float4* wkr = (const float4*)(Wk + (size_t)t * D);
        const float4* rr  = (const float4*)row;
        float acc = 0.f;
        #pragma unroll 4
        for (int i = 0; i < D / 4; ++i) {
            float4 a = rr[i]; float4 b = wkr[i];
            acc += a.x * b.x + a.y * b.y + a.z * b.z + a.w * b.w;
        }
        M[k * D + t] = acc;
        float p = row[t] * bk[t];
        float s = block_reduce_256(p, sred);
        if (t == 0) wb[k] = s;
    } else {
        row[t] = bq[t];
        __syncthreads();
        const float4* wkr = (const float4*)(Wk + (size_t)t * D);
        const float4* rr  = (const float4*)row;
        float acc = 0.f;
        #pragma unroll 4
        for (int i = 0; i < D / 4; ++i) {
            float4 a = rr[i]; float4 b = wkr[i];
            acc += a.x * b.x + a.y * b.y + a.z * b.z + a.w * b.w;
        }
        bqt[t] = acc;
        float p = row[t] * bk[t];
        float s = block_reduce_256(p, sred);
        if (t == 0) c0[0] = s;
    }
}

// Kernel B: qt = uq @ M + bqt   [U,D], K=QD. 8 rows/block, NO LDS:
// A-row slices are wave-uniform -> direct uniform float4 loads (broadcast /
// scalarized to s_load by uniformity analysis). Deletes the LDS staging pass,
// 2 barriers, and 16 ds_read_b128 per K-iter that dominated issue bandwidth.
__global__ void __launch_bounds__(256, 8) upa_qt(
    const float* __restrict__ uq, const float* __restrict__ M,
    const float* __restrict__ bqt, float* __restrict__ qt) {
    int u0 = blockIdx.x * BMG;
    int t = threadIdx.x;
    const float* A0 = uq + (size_t)u0 * QD;
    float acc[BMG];
    #pragma unroll
    for (int r = 0; r < BMG; ++r) acc[r] = 0.f;
    for (int k8 = 0; k8 < QD; k8 += 8) {
        float m[8];
        #pragma unroll
        for (int i = 0; i < 8; ++i) m[i] = M[(size_t)(k8 + i) * D + t];
        #pragma unroll
        for (int r = 0; r < BMG; ++r) {
            const float4* Ar = (const float4*)(A0 + (size_t)r * QD + k8);
            float4 a0 = Ar[0];
            float4 a1 = Ar[1];
            acc[r] += a0.x * m[0] + a0.y * m[1] + a0.z * m[2] + a0.w * m[3]
                    + a1.x * m[4] + a1.y * m[5] + a1.z * m[6] + a1.w * m[7];
        }
    }
    float bb = bqt[t];
    #pragma unroll
    for (int r = 0; r < BMG; ++r) qt[(size_t)(u0 + r) * D + t] = acc[r] + bb;
}

// Kernel C: SINGLE-PASS + DPP-reduce (r6/r7, best measured: ~71µs, VGPR=32,
// no scratch, FETCH pinned at 205MB @ ~2.9TB/s random-fill ceiling).
// UNCHANGED.
__global__ void __launch_bounds__(256, 5) upa_attn(
    const float* __restrict__ qt, const float* __restrict__ uq,
    const float* __restrict__ wb, const float* __restrict__ c0,
    const float* __restrict__ feats, const int* __restrict__ item_idx,
    float* __restrict__ agg, float* __restrict__ sw) {
    __shared__ float pagg[4][D];    // 4 KB cross-wave partials
    __shared__ float pE[4], pS[4];
    int u = blockIdx.x;
    int t = threadIdx.x;
    int wave = t >> 6, lane = t & 63;

    // wave-local qb = uq[u,:].wb + c0 (DPP sum, no barrier)
    float p = uq[(size_t)u * QD + lane] * wb[lane]
            + uq[(size_t)u * QD + 64 + lane] * wb[64 + lane];
    float qb = wave_bcast_sum64(p) + c0[0];

    // full qt row in one b128 per lane
    float4 q = ((const float4*)(qt + (size_t)u * D))[lane];

    // 50 indices live in lanes 0..49; broadcast via readlane (SGPR base)
    int ll = lane < H ? lane : H - 1;
    int idxv = item_idx[(size_t)u * H + ll];

    // single pass: each feats row loaded once, consumed immediately
    float4 acc = make_float4(0.f, 0.f, 0.f, 0.f);
    float E = 0.f, S = 0.f;
    #pragma unroll
    for (int r = 0; r < NRMAX; ++r) {
        int j = 4 * r + wave;
        if (j < H) {
            int sidx = __builtin_amdgcn_readlane(idxv, j);
            float4 v = ((const float4*)(feats + (size_t)sidx * D))[lane];
            float part = v.x * q.x + v.y * q.y + v.z * q.z + v.w * q.w;
            float s = wave_bcast_sum64(part) + qb;
            float e = __expf(s);
            S += s;
            E += e;
            acc.x += e * v.x;
            acc.y += e * v.y;
            acc.z += e * v.z;
            acc.w += e * v.w;
        }
    }

    // cross-wave combine (the only barrier in the kernel)
    ((float4*)pagg[wave])[lane] = acc;
    if (lane == 0) { pE[wave] = E; pS[wave] = S; }
    __syncthreads();
    float Et = pE[0] + pE[1] + pE[2] + pE[3];
    float St = pS[0] + pS[1] + pS[2] + pS[3];
    float inv = 1.f / (Et + 1e-12f * __expf(St));
    agg[(size_t)u * D + t] =
        (pagg[0][t] + pagg[1][t] + pagg[2][t] + pagg[3][t]) * inv;
    if (t == 0) sw[u] = Et * inv;
}

// Kernel D: out = agg @ Wv + bv * sw[u]   [U,D], K=D. 8 rows/block, NO LDS
// (same uniform-load structure as kernel B).
__global__ void __launch_bounds__(256, 8) upa_out(
    const float* __restrict__ agg, const float* __restrict__ Wv,
    const float* __restrict__ bv, const float* __restrict__ sw,
    float* __restrict__ out) {
    int u0 = blockIdx.x * BMG;
    int t = threadIdx.x;
    const float* A0 = agg + (size_t)u0 * D;
    float acc[BMG];
    #pragma unroll
    for (int r = 0; r < BMG; ++r) acc[r] = 0.f;
    for (int k8 = 0; k8 < D; k8 += 8) {
        float m[8];
        #pragma unroll
        for (int i = 0; i < 8; ++i) m[i] = Wv[(size_t)(k8 + i) * D + t];
        #pragma unroll
        for (int r = 0; r < BMG; ++r) {
            const float4* Ar = (const float4*)(A0 + (size_t)r * D + k8);
            float4 a0 = Ar[0];
            float4 a1 = Ar[1];
            acc[r] += a0.x * m[0] + a0.y * m[1] + a0.z * m[2] + a0.w * m[3]
                    + a1.x * m[4] + a1.y * m[5] + a1.z * m[6] + a1.w * m[7];
        }
    }
    float b = bv[t];
    #pragma unroll
    for (int r = 0; r < BMG; ++r)
        out[(size_t)(u0 + r) * D + t] = acc[r] + b * sw[u0 + r];
}

extern "C" void kernel_launch(void* const* d_in, const int* in_sizes, int n_in,
                              void* d_out, int out_size, void* d_ws, size_t ws_size,
                              hipStream_t stream) {
    const float* uq    = (const float*)d_in[0];   // [U,QD]
    const float* feats = (const float*)d_in[1];   // [N,D]
    const float* Wq    = (const float*)d_in[2];   // [QD,D]
    const float* bq    = (const float*)d_in[3];   // [D]
    const float* Wk    = (const float*)d_in[4];   // [D,D]
    const float* bk    = (const float*)d_in[5];   // [D]
    const float* Wv    = (const float*)d_in[6];   // [D,D]
    const float* bv    = (const float*)d_in[7];   // [D]
    // d_in[8] = batch_user_indices: structurally repeat(arange(U),H) -> implicit
    const int* item_idx = (const int*)d_in[9];    // [E]
    float* out = (float*)d_out;

    float* ws  = (float*)d_ws;
    float* M   = ws;                    // QD*D   = 32768
    float* bqt = M + QD * D;            // D      = 256
    float* wb  = bqt + D;               // QD     = 128
    float* c0  = wb + QD;               // 4 (padded)
    float* qt  = c0 + 4;                // U*D    = 2097152
    float* agg = qt + (size_t)U * D;    // U*D    = 2097152
    float* sw  = agg + (size_t)U * D;   // U      = 8192

    upa_precompute<<<QD + 1, 256, 0, stream>>>(Wq, bq, Wk, bk, M, bqt, wb, c0);
    upa_qt<<<U / BMG, 256, 0, stream>>>(uq, M, bqt, qt);
    upa_attn<<<U, 256, 0, stream>>>(qt, uq, wb, c0, feats, item_idx, agg, sw);
    upa_out<<<U / BMG, 256, 0, stream>>>(agg, Wv, bv, sw, out);
}

// Round 9
// 104.970 us; speedup vs baseline: 1.2089x; 1.2089x over previous
//
#include <hip/hip_runtime.h>
#include <math.h>

#define U 8192
#define NITEMS 100000
#define H 50
#define QD 128
#define D 256
#define BMG 8      // users per fused block (grid = U/BMG = 1024)

// Full-wave (64-lane) sum via DPP, result broadcast through readlane(63).
__device__ __forceinline__ float wave_bcast_sum64(float x) {
    float t = x;
    int y;
    y = __builtin_amdgcn_update_dpp(0, __float_as_int(t), 0xB1, 0xF, 0xF, true); // quad_perm(1,0,3,2)
    t += __int_as_float(y);
    y = __builtin_amdgcn_update_dpp(0, __float_as_int(t), 0x4E, 0xF, 0xF, true); // quad_perm(2,3,0,1)
    t += __int_as_float(y);
    y = __builtin_amdgcn_update_dpp(0, __float_as_int(t), 0x124, 0xF, 0xF, true); // row_ror:4
    t += __int_as_float(y);
    y = __builtin_amdgcn_update_dpp(0, __float_as_int(t), 0x128, 0xF, 0xF, true); // row_ror:8
    t += __int_as_float(y);
    y = __builtin_amdgcn_update_dpp(0, __float_as_int(t), 0x142, 0xA, 0xF, true); // row_bcast:15
    t += __int_as_float(y);
    y = __builtin_amdgcn_update_dpp(0, __float_as_int(t), 0x143, 0xC, 0xF, true); // row_bcast:31
    t += __int_as_float(y);
    return __int_as_float(__builtin_amdgcn_readlane(__float_as_int(t), 63));
}

// broadcast block-reduce (256 threads = 4 waves) — kernel A only
__device__ __forceinline__ float block_reduce_256(float v, float* sred) {
    #pragma unroll
    for (int off = 32; off >= 1; off >>= 1)
        v += __shfl_xor(v, off, 64);
    int wave = threadIdx.x >> 6;
    int lane = threadIdx.x & 63;
    if (lane == 0) sred[wave] = v;
    __syncthreads();
    float s;
    if (threadIdx.x == 0) {
        s = sred[0] + sred[1] + sred[2] + sred[3];
        sred[0] = s;
    }
    __syncthreads();
    s = sred[0];
    __syncthreads();
    return s;
}

// Kernel A: M = Wq @ Wk^T [QD,D]; bqt = bq @ Wk^T [D]; wb = Wq @ bk [QD]; c0 = bq.bk
__global__ void __launch_bounds__(256) upa_precompute(
    const float* __restrict__ Wq, const float* __restrict__ bq,
    const float* __restrict__ Wk, const float* __restrict__ bk,
    float* __restrict__ M, float* __restrict__ bqt,
    float* __restrict__ wb, float* __restrict__ c0) {
    __shared__ float row[D];
    __shared__ float sred[4];
    int k = blockIdx.x;
    int t = threadIdx.x;
    if (k < QD) {
        row[t] = (t < D) ? Wq[k * D + t] : 0.f;
        __syncthreads();
        const float4* wkr = (const float4*)(Wk + (size_t)t * D);
        const float4* rr  = (const float4*)row;
        float acc = 0.f;
        #pragma unroll 4
        for (int i = 0; i < D / 4; ++i) {
            float4 a = rr[i]; float4 b = wkr[i];
            acc += a.x * b.x + a.y * b.y + a.z * b.z + a.w * b.w;
        }
        M[k * D + t] = acc;
        float p = row[t] * bk[t];
        float s = block_reduce_256(p, sred);
        if (t == 0) wb[k] = s;
    } else {
        row[t] = bq[t];
        __syncthreads();
        const float4* wkr = (const float4*)(Wk + (size_t)t * D);
        const float4* rr  = (const float4*)row;
        float acc = 0.f;
        #pragma unroll 4
        for (int i = 0; i < D / 4; ++i) {
            float4 a = rr[i]; float4 b = wkr[i];
            acc += a.x * b.x + a.y * b.y + a.z * b.z + a.w * b.w;
        }
        bqt[t] = acc;
        float p = row[t] * bk[t];
        float s = block_reduce_256(p, sred);
        if (t == 0) c0[0] = s;
    }
}

// Fused kernel: B-phase (qt rows -> LDS), C-phase (single-pass DPP attention,
// 2 users per wave, 50 rows each, no cross-wave combine), D-phase (out GEMV
// from agg_s in LDS). Deletes 2 launches, 17MB qt/agg global round-trip, and
// the cross-wave partial combine. Weight L2 traffic unchanged (M/Wv read once
// per 8 users, as before). C-phase identity (absmax-stable r1-r8):
//   w_j = exp(s_j)/(sum_k exp(s_k) + 1e-12*exp(S)),  S = sum_k s_k
__global__ void __launch_bounds__(256, 4) upa_fused(
    const float* __restrict__ uq, const float* __restrict__ M,
    const float* __restrict__ bqt, const float* __restrict__ wb,
    const float* __restrict__ c0, const float* __restrict__ feats,
    const int* __restrict__ item_idx, const float* __restrict__ Wv,
    const float* __restrict__ bv, float* __restrict__ out) {
    __shared__ float A[BMG][QD];     // 4 KB  uq rows
    __shared__ float qt_s[BMG][D];   // 8 KB
    __shared__ float agg_s[BMG][D];  // 8 KB
    __shared__ float sw_s[BMG];
    int u0 = blockIdx.x * BMG;
    int t = threadIdx.x;
    int wave = t >> 6, lane = t & 63;
    int uwA = 2 * wave, uwB = 2 * wave + 1;

    // early independent loads: this wave's two users' history indices
    int ll = lane < H ? lane : H - 1;
    int idxA = item_idx[(size_t)(u0 + uwA) * H + ll];
    int idxB = item_idx[(size_t)(u0 + uwB) * H + ll];

    // stage uq rows
    {
        const float4* src = (const float4*)(uq + (size_t)u0 * QD);
        float4* dst = (float4*)&A[0][0];
        for (int i = t; i < BMG * QD / 4; i += 256) dst[i] = src[i];
    }
    __syncthreads();

    // ---- B-phase: qt_s[r][t] = uq[u0+r,:] @ M[:,t] + bqt[t] ----
    {
        float acc[BMG];
        #pragma unroll
        for (int r = 0; r < BMG; ++r) acc[r] = 0.f;
        for (int k8 = 0; k8 < QD; k8 += 8) {
            float m[8];
            #pragma unroll
            for (int i = 0; i < 8; ++i) m[i] = M[(size_t)(k8 + i) * D + t];
            #pragma unroll
            for (int r = 0; r < BMG; ++r) {
                float4 a0 = *((const float4*)&A[r][k8]);
                float4 a1 = *((const float4*)&A[r][k8 + 4]);
                acc[r] += a0.x * m[0] + a0.y * m[1] + a0.z * m[2] + a0.w * m[3]
                        + a1.x * m[4] + a1.y * m[5] + a1.z * m[6] + a1.w * m[7];
            }
        }
        float bb = bqt[t];
        #pragma unroll
        for (int r = 0; r < BMG; ++r) qt_s[r][t] = acc[r] + bb;
    }

    // qb for this wave's users (from staged A-tile; no barrier needed yet)
    float pA = A[uwA][lane] * wb[lane] + A[uwA][64 + lane] * wb[64 + lane];
    float qbA = wave_bcast_sum64(pA) + c0[0];
    float pB = A[uwB][lane] * wb[lane] + A[uwB][64 + lane] * wb[64 + lane];
    float qbB = wave_bcast_sum64(pB) + c0[0];
    __syncthreads();   // qt_s ready

    // ---- C-phase: single-pass attention, 2 users per wave, 2-way ILP ----
    float4 qA = ((const float4*)qt_s[uwA])[lane];
    float4 qB = ((const float4*)qt_s[uwB])[lane];

    float4 accA = make_float4(0.f, 0.f, 0.f, 0.f);
    float4 accB = make_float4(0.f, 0.f, 0.f, 0.f);
    float EA = 0.f, SA = 0.f, EB = 0.f, SB = 0.f;
    #pragma unroll 2
    for (int j = 0; j < H; ++j) {
        int sA = __builtin_amdgcn_readlane(idxA, j);
        int sB = __builtin_amdgcn_readlane(idxB, j);
        float4 vA = ((const float4*)(feats + (size_t)sA * D))[lane];
        float4 vB = ((const float4*)(feats + (size_t)sB * D))[lane];
        float dA = vA.x * qA.x + vA.y * qA.y + vA.z * qA.z + vA.w * qA.w;
        float dB = vB.x * qB.x + vB.y * qB.y + vB.z * qB.z + vB.w * qB.w;
        float sfA = wave_bcast_sum64(dA) + qbA;
        float sfB = wave_bcast_sum64(dB) + qbB;
        float eA = __expf(sfA);
        float eB = __expf(sfB);
        SA += sfA; EA += eA;
        SB += sfB; EB += eB;
        accA.x += eA * vA.x; accA.y += eA * vA.y;
        accA.z += eA * vA.z; accA.w += eA * vA.w;
        accB.x += eB * vB.x; accB.y += eB * vB.y;
        accB.z += eB * vB.z; accB.w += eB * vB.w;
    }
    float invA = 1.f / (EA + 1e-12f * __expf(SA));
    float invB = 1.f / (EB + 1e-12f * __expf(SB));
    ((float4*)agg_s[uwA])[lane] =
        make_float4(accA.x * invA, accA.y * invA, accA.z * invA, accA.w * invA);
    ((float4*)agg_s[uwB])[lane] =
        make_float4(accB.x * invB, accB.y * invB, accB.z * invB, accB.w * invB);
    if (lane == 0) { sw_s[uwA] = EA * invA; sw_s[uwB] = EB * invB; }
    __syncthreads();   // agg_s ready

    // ---- D-phase: out[u0+r, t] = agg_s[r,:] @ Wv[:,t] + bv[t]*sw_s[r] ----
    {
        float acc[BMG];
        #pragma unroll
        for (int r = 0; r < BMG; ++r) acc[r] = 0.f;
        for (int k8 = 0; k8 < D; k8 += 8) {
            float m[8];
            #pragma unroll
            for (int i = 0; i < 8; ++i) m[i] = Wv[(size_t)(k8 + i) * D + t];
            #pragma unroll
            for (int r = 0; r < BMG; ++r) {
                float4 a0 = *((const float4*)&agg_s[r][k8]);
                float4 a1 = *((const float4*)&agg_s[r][k8 + 4]);
                acc[r] += a0.x * m[0] + a0.y * m[1] + a0.z * m[2] + a0.w * m[3]
                        + a1.x * m[4] + a1.y * m[5] + a1.z * m[6] + a1.w * m[7];
            }
        }
        float b = bv[t];
        #pragma unroll
        for (int r = 0; r < BMG; ++r)
            out[(size_t)(u0 + r) * D + t] = acc[r] + b * sw_s[r];
    }
}

extern "C" void kernel_launch(void* const* d_in, const int* in_sizes, int n_in,
                              void* d_out, int out_size, void* d_ws, size_t ws_size,
                              hipStream_t stream) {
    const float* uq    = (const float*)d_in[0];   // [U,QD]
    const float* feats = (const float*)d_in[1];   // [N,D]
    const float* Wq    = (const float*)d_in[2];   // [QD,D]
    const float* bq    = (const float*)d_in[3];   // [D]
    const float* Wk    = (const float*)d_in[4];   // [D,D]
    const float* bk    = (const float*)d_in[5];   // [D]
    const float* Wv    = (const float*)d_in[6];   // [D,D]
    const float* bv    = (const float*)d_in[7];   // [D]
    // d_in[8] = batch_user_indices: structurally repeat(arange(U),H) -> implicit
    const int* item_idx = (const int*)d_in[9];    // [E]
    float* out = (float*)d_out;

    float* ws  = (float*)d_ws;
    float* M   = ws;                    // QD*D   = 32768
    float* bqt = M + QD * D;            // D      = 256
    float* wb  = bqt + D;               // QD     = 128
    float* c0  = wb + QD;               // 4 (padded)

    upa_precompute<<<QD + 1, 256, 0, stream>>>(Wq, bq, Wk, bk, M, bqt, wb, c0);
    upa_fused<<<U / BMG, 256, 0, stream>>>(uq, M, bqt, wb, c0, feats, item_idx,
                                           Wv, bv, out);
}